// Round 12
// baseline (173.864 us; speedup 1.0000x reference)
//
#include <hip/hip_runtime.h>
#include <stdint.h>

// DenseAttention_61598420959334 — round 12: TLP decoupling.
//   k_cvt   : streaming x f32 -> x16 bf16 (2048 blocks, fill-like TLP)
//   k_gram16: bf16 gram, 1024 blocks x 4 waves, wave-column split,
//             tr-read frags, direct disjoint partial dump (no LDS reduce)
//   k_reduce/k_mid/k_out16 from r11 (verified); cascading ws fallbacks.

#define DD 128
#define PART_STRIDE 16512  // 16384 G-partial + 128 s-partial
#define TILE_SH 5184       // shorts per 32x128 tr-subtiled bf16 tile
#define TILE_B  10368      // bytes per tile

typedef float f32x4 __attribute__((ext_vector_type(4)));
typedef short s16x8 __attribute__((ext_vector_type(8)));
typedef float fvec4 __attribute__((ext_vector_type(4)));
typedef unsigned int u32x4 __attribute__((ext_vector_type(4)));

__device__ __forceinline__ unsigned short f2bf(float f) {
    union { float f; uint32_t u; } v; v.f = f;
    uint32_t u = v.u;
    u += 0x7FFFu + ((u >> 16) & 1u);
    return (unsigned short)(u >> 16);
}
__device__ __forceinline__ s16x8 mk8(uint64_t lo, uint64_t hi) {
    union { uint64_t u[2]; s16x8 v; } x; x.u[0] = lo; x.u[1] = hi; return x.v;
}

// ----------------------------------------- k_cvt: x f32 -> x16 bf16 (stream)
__global__ __launch_bounds__(256) void k_cvt(const float* __restrict__ x,
                                             unsigned short* __restrict__ x16) {
    const long stride = (long)gridDim.x * 256;
    const long i0 = (long)blockIdx.x * 256 + threadIdx.x;
    const fvec4* xg = (const fvec4*)x;
    fvec4 va[8], vb[8];
#pragma unroll
    for (int k = 0; k < 8; ++k) {
        long i = i0 + k * stride;
        va[k] = xg[2 * i];
        vb[k] = xg[2 * i + 1];
    }
#pragma unroll
    for (int k = 0; k < 8; ++k) {
        long i = i0 + k * stride;
        uint32_t h0, h1, h2, h3;
        asm("v_cvt_pk_bf16_f32 %0, %1, %2" : "=v"(h0) : "v"(va[k][0]), "v"(va[k][1]));
        asm("v_cvt_pk_bf16_f32 %0, %1, %2" : "=v"(h1) : "v"(va[k][2]), "v"(va[k][3]));
        asm("v_cvt_pk_bf16_f32 %0, %1, %2" : "=v"(h2) : "v"(vb[k][0]), "v"(vb[k][1]));
        asm("v_cvt_pk_bf16_f32 %0, %1, %2" : "=v"(h3) : "v"(vb[k][2]), "v"(vb[k][3]));
        u32x4 o; o[0] = h0; o[1] = h1; o[2] = h2; o[3] = h3;
        *(u32x4*)&x16[i * 8] = o;
    }
}

// ---------------------------- k_gram16: bf16 gram, wave-column split partials
__global__ __launch_bounds__(256, 3) void k_gram16(const unsigned short* __restrict__ x16,
                                                   float* __restrict__ ws,
                                                   int rows_per_blk) {
    __shared__ __align__(16) short lds[2][TILE_SH];  // 20.7 KB double buffer
    const int t = threadIdx.x;
    const int l = t & 63, w = t >> 6;
    const long rowbase = (long)blockIdx.x * rows_per_blk;

    s16x8 ones;
#pragma unroll
    for (int i = 0; i < 8; ++i) ones[i] = (short)0x3F80;

    f32x4 acc[8][2] = {};   // G[a-block][32w+16j block], static-indexed
    f32x4 accs[2] = {};     // colsum partials (ones-MFMA)

    const unsigned base0 = (unsigned)(uintptr_t)&lds[0][0];

    // staging geometry: idx = q*256 + t; j = idx>>4, d0 = (idx&15)*8
    const int j0 = t >> 4,        d0a = (t & 15) * 8;
    const int j1 = 16 + (t >> 4), d0b = d0a;
    const int off0 = 648 * (d0a >> 4) + 320 * ((j0 >> 2) & 1) + 64 * (j0 >> 3) +
                     16 * (j0 & 3) + (d0a & 15);
    const int off1 = 648 * (d0b >> 4) + 320 * ((j1 >> 2) & 1) + 64 * (j1 >> 3) +
                     16 * (j1 & 3) + (d0b & 15);
    const long go0 = (long)j0 * 128 + d0a;
    const long go1 = (long)j1 * 128 + d0b;

#define STAGE16(BUF, TL) do {                                                   \
        long rb = (rowbase + (long)(TL) * 32) * 128;                            \
        s16x8 g0 = *(const s16x8*)&x16[rb + go0];                               \
        s16x8 g1 = *(const s16x8*)&x16[rb + go1];                               \
        *(s16x8*)&lds[BUF][off0] = g0;                                          \
        *(s16x8*)&lds[BUF][off1] = g1;                                          \
    } while (0)

    // b-frags selected by ADDRESS (wave-uniform w), never by runtime array idx
#define GRAM16(BUF) do {                                                        \
        uint64_t fr[8][2], fbr[2][2];                                           \
        _Pragma("unroll")                                                       \
        for (int a = 0; a < 8; ++a)                                             \
            _Pragma("unroll")                                                   \
            for (int r = 0; r < 2; ++r) {                                       \
                unsigned ad = base0 + (unsigned)((BUF) * TILE_B + a * 1296 +    \
                                                 r * 640) + 8u * (unsigned)l;   \
                asm volatile("ds_read_b64_tr_b16 %0, %1"                        \
                             : "=v"(fr[a][r]) : "v"(ad));                       \
            }                                                                   \
        _Pragma("unroll")                                                       \
        for (int j = 0; j < 2; ++j)                                             \
            _Pragma("unroll")                                                   \
            for (int r = 0; r < 2; ++r) {                                       \
                unsigned ad = base0 + (unsigned)((BUF) * TILE_B + r * 640) +    \
                              1296u * (unsigned)(2 * w + j) + 8u * (unsigned)l; \
                asm volatile("ds_read_b64_tr_b16 %0, %1"                        \
                             : "=v"(fbr[j][r]) : "v"(ad));                      \
            }                                                                   \
        asm volatile("s_waitcnt lgkmcnt(0)" ::: "memory");                      \
        __builtin_amdgcn_sched_barrier(0);                                      \
        s16x8 fg[8], fb[2];                                                     \
        _Pragma("unroll")                                                       \
        for (int a = 0; a < 8; ++a) fg[a] = mk8(fr[a][0], fr[a][1]);            \
        _Pragma("unroll")                                                       \
        for (int j = 0; j < 2; ++j) fb[j] = mk8(fbr[j][0], fbr[j][1]);          \
        _Pragma("unroll")                                                       \
        for (int a = 0; a < 8; ++a)                                             \
            _Pragma("unroll")                                                   \
            for (int j = 0; j < 2; ++j)                                         \
                acc[a][j] = __builtin_amdgcn_mfma_f32_16x16x32_bf16(            \
                    fg[a], fb[j], acc[a][j], 0, 0, 0);                          \
        accs[0] = __builtin_amdgcn_mfma_f32_16x16x32_bf16(ones, fb[0], accs[0], 0, 0, 0); \
        accs[1] = __builtin_amdgcn_mfma_f32_16x16x32_bf16(ones, fb[1], accs[1], 0, 0, 0); \
    } while (0)

    const int ntiles = rows_per_blk >> 5;
    STAGE16(0, 0);
    __syncthreads();
#pragma unroll 1
    for (int tl = 0; tl < ntiles; ++tl) {
        if (tl + 1 < ntiles) STAGE16((tl + 1) & 1, tl + 1);
        GRAM16(tl & 1);
        __syncthreads();
    }

    // disjoint partial dump: wave w owns cols [32w, 32w+32) — no reduction
    long pbase = (long)blockIdx.x * PART_STRIDE;
#pragma unroll
    for (int a = 0; a < 8; ++a)
#pragma unroll
        for (int j = 0; j < 2; ++j)
#pragma unroll
            for (int e = 0; e < 4; ++e) {
                int row = a * 16 + (l >> 4) * 4 + e;
                int col = 32 * w + 16 * j + (l & 15);
                ws[pbase + row * 128 + col] = acc[a][j][e];
            }
    if (l < 16) {
        ws[pbase + 16384 + 32 * w + l]      = accs[0][0];
        ws[pbase + 16384 + 32 * w + 16 + l] = accs[1][0];
    }
#undef STAGE16
#undef GRAM16
}

// ---------- fallback gram (f32 input, r11-verified) if x16 doesn't fit ws
__global__ __launch_bounds__(256) void k_gram_f32(const float* __restrict__ x,
                                                  float* __restrict__ ws) {
    __shared__ __align__(16) unsigned char smem[66048];
    short* tiles = (short*)smem;
    float* grid  = (float*)smem;
    float* sgrid = (float*)(smem + 65536);

    const int t = threadIdx.x;
    const int l = t & 63, w = t >> 6;
    const long rowbase = (long)blockIdx.x * 512 + (long)w * 128;
    const fvec4* xg = (const fvec4*)x;
    short* myt = tiles + w * TILE_SH;
    const unsigned mybase = (unsigned)(uintptr_t)myt;

    f32x4 acc[36] = {};
    float sacc0 = 0.f, sacc1 = 0.f, sacc2 = 0.f, sacc3 = 0.f;
    const int jrow = l >> 5;
    const int cq   = l & 31;

#pragma unroll 1
    for (int tl = 0; tl < 4; ++tl) {
        long r0 = rowbase + tl * 32;
        fvec4 va[8], vb[8];
#pragma unroll
        for (int i = 0; i < 8; ++i) va[i] = xg[(r0 + 2 * i + jrow) * 32 + cq];
#pragma unroll
        for (int i = 0; i < 8; ++i) vb[i] = xg[(r0 + 2 * (i + 8) + jrow) * 32 + cq];

#pragma unroll
        for (int i = 0; i < 16; ++i) {
            fvec4 v = (i < 8) ? va[i & 7] : vb[i & 7];
            int j = 2 * i + jrow;
            int d0 = 4 * cq;
            uint32_t h0, h1;
            asm("v_cvt_pk_bf16_f32 %0, %1, %2" : "=v"(h0) : "v"(v[0]), "v"(v[1]));
            asm("v_cvt_pk_bf16_f32 %0, %1, %2" : "=v"(h1) : "v"(v[2]), "v"(v[3]));
            uint64_t ph = (uint64_t)h0 | ((uint64_t)h1 << 32);
            int off = 648 * (d0 >> 4) + 320 * ((j >> 2) & 1) + 64 * (j >> 3) +
                      16 * (j & 3) + (d0 & 15);
            *(uint64_t*)&myt[off] = ph;
            sacc0 += v[0]; sacc1 += v[1]; sacc2 += v[2]; sacc3 += v[3];
        }
        asm volatile("s_waitcnt lgkmcnt(0)" ::: "memory");
        __builtin_amdgcn_sched_barrier(0);

        uint64_t fr[8][2];
#pragma unroll
        for (int a = 0; a < 8; ++a)
#pragma unroll
            for (int r = 0; r < 2; ++r) {
                unsigned ad = mybase + (unsigned)(a * 1296 + r * 640) + 8u * (unsigned)l;
                asm volatile("ds_read_b64_tr_b16 %0, %1" : "=v"(fr[a][r]) : "v"(ad));
            }
        asm volatile("s_waitcnt lgkmcnt(0)" ::: "memory");
        __builtin_amdgcn_sched_barrier(0);

        s16x8 fg[8];
#pragma unroll
        for (int a = 0; a < 8; ++a) fg[a] = mk8(fr[a][0], fr[a][1]);
        {
            int idx = 0;
#pragma unroll
            for (int a = 0; a < 8; ++a)
#pragma unroll
                for (int b = a; b < 8; ++b) {
                    acc[idx] = __builtin_amdgcn_mfma_f32_16x16x32_bf16(
                        fg[a], fg[b], acc[idx], 0, 0, 0);
                    ++idx;
                }
        }
    }

    sacc0 += __shfl_xor(sacc0, 32);
    sacc1 += __shfl_xor(sacc1, 32);
    sacc2 += __shfl_xor(sacc2, 32);
    sacc3 += __shfl_xor(sacc3, 32);

    __syncthreads();
    for (int ph = 0; ph < 4; ++ph) {
        if (w == ph) {
            int idx = 0;
#pragma unroll
            for (int a = 0; a < 8; ++a)
#pragma unroll
                for (int b = a; b < 8; ++b) {
#pragma unroll
                    for (int e = 0; e < 4; ++e) {
                        int row = a * 16 + (l >> 4) * 4 + e;
                        int col = b * 16 + (l & 15);
                        float val = acc[idx][e];
                        if (ph == 0) {
                            grid[row * 128 + col] = val;
                            if (a != b) grid[col * 128 + row] = val;
                        } else {
                            grid[row * 128 + col] += val;
                            if (a != b) grid[col * 128 + row] += val;
                        }
                    }
                    ++idx;
                }
            if (l < 32) {
                if (ph == 0) {
                    sgrid[4 * l + 0] = sacc0; sgrid[4 * l + 1] = sacc1;
                    sgrid[4 * l + 2] = sacc2; sgrid[4 * l + 3] = sacc3;
                } else {
                    sgrid[4 * l + 0] += sacc0; sgrid[4 * l + 1] += sacc1;
                    sgrid[4 * l + 2] += sacc2; sgrid[4 * l + 3] += sacc3;
                }
            }
        }
        __syncthreads();
    }

    long pbase = (long)blockIdx.x * PART_STRIDE;
    for (int i = t; i < 16384; i += 256) ws[pbase + i] = grid[i];
    if (t < 128) ws[pbase + 16384 + t] = sgrid[t];
}

// ------------------------------------------------------- reduce partials -> G, s
__global__ __launch_bounds__(256) void k_reduce(const float* __restrict__ parts,
                                                float* __restrict__ g_out,
                                                float* __restrict__ s_out, int nb1) {
    __shared__ float red[256];
    int b = blockIdx.x, t = threadIdx.x;
    if (b < 512) {
        int d1 = b >> 2, q = b & 3;
        int c32 = t & 31, pg = t >> 5;
        int per = nb1 >> 3;
        int e = d1 * 128 + q * 32 + c32;
        float acc = 0.f;
#pragma unroll 4
        for (int p = pg * per; p < (pg + 1) * per; ++p)
            acc += parts[(long)p * PART_STRIDE + e];
        red[t] = acc;
        __syncthreads();
        if (pg == 0) {
            float s = red[c32];
#pragma unroll
            for (int k = 1; k < 8; ++k) s += red[k * 32 + c32];
            g_out[e] = s;
        }
    } else {
        int ee = t & 127, hg = t >> 7;
        int per = nb1 >> 1;
        float acc = 0.f;
#pragma unroll 4
        for (int p = hg * per; p < (hg + 1) * per; ++p)
            acc += parts[(long)p * PART_STRIDE + 16384 + ee];
        red[t] = acc;
        __syncthreads();
        if (hg == 0) s_out[ee] = red[ee] + red[128 + ee];
    }
}

// ---- k_mid: scores row a from G (in LDS) + softmax + M row + c/wsum + casts
__global__ __launch_bounds__(256) void k_mid(const float* __restrict__ G,
                                             const float* __restrict__ s,
                                             const float* __restrict__ Wq,
                                             const float* __restrict__ bq,
                                             const float* __restrict__ Wk,
                                             const float* __restrict__ bk,
                                             const float* __restrict__ Wv,
                                             const float* __restrict__ bv,
                                             const float* __restrict__ Wo,
                                             unsigned short* __restrict__ M16,
                                             unsigned short* __restrict__ Wo16,
                                             float* __restrict__ cvec,
                                             float* __restrict__ wsum, float Bn) {
    __shared__ float gl[16384];
    __shared__ float wk[128 * 129];
    __shared__ float wqr[128], sl[128], bkl[128], bvl[128];
    __shared__ float prt[2][128], prt2[2][128];
    __shared__ float tmp[128], scl[128], wrow[128], scl2[128];
    int t = threadIdx.x, a = blockIdx.x;
    int tt = t & 127, seg = t >> 7;

    {
        const fvec4* gg = (const fvec4*)G;
        fvec4* gs = (fvec4*)gl;
        for (int i = t; i < 4096; i += 256) gs[i] = gg[i];
    }
    for (int idx = t; idx < 16384; idx += 256) {
        int r = idx >> 7, cc = idx & 127;
        wk[r * 129 + cc] = Wk[idx];
    }
    if (t < 128) {
        wqr[t] = Wq[a * 128 + t];
        sl[t] = s[t]; bkl[t] = bk[t]; bvl[t] = bv[t];
    }
    __syncthreads();

    float tm = 0.f;
#pragma unroll 8
    for (int d1 = seg * 64; d1 < seg * 64 + 64; ++d1) tm += wqr[d1] * gl[d1 * 128 + tt];
    prt[seg][tt] = tm;
    __syncthreads();
    if (t < 128) tmp[t] = prt[0][t] + prt[1][t];
    __syncthreads();

    float p1 = 0.f, p2 = 0.f;
#pragma unroll 8
    for (int d = seg * 64; d < seg * 64 + 64; ++d) {
        float w2 = wk[tt * 129 + d];
        p1 += tmp[d] * w2;
        p2 += sl[d] * w2;
    }
    prt[seg][tt] = p1;
    prt2[seg][tt] = p2;
    __syncthreads();
    if (t < 128) {
        float tdot = prt[0][t] + prt[1][t];
        float kdot = prt2[0][t] + prt2[1][t];
        float qs = 0.f;
#pragma unroll 8
        for (int d = 0; d < 128; ++d) qs += wqr[d] * sl[d];
        float bqa = bq[a];
        float sc = (tdot + qs * bkl[t] + bqa * kdot + Bn * bqa * bkl[t]) *
                   0.0883883476483184406f;
        scl[t] = sc;
    }
    __syncthreads();
    if (t < 128) {
        float mx = -1e30f;
        for (int i2 = 0; i2 < 128; ++i2) mx = fmaxf(mx, scl[i2]);
        scl2[t] = expf(scl[t] - mx);
    }
    __syncthreads();
    if (t < 128) {
        float sum = 0.f;
        for (int i2 = 0; i2 < 128; ++i2) sum += scl2[i2];
        wrow[t] = scl2[t] / sum;
    }
    __syncthreads();

    float pm = 0.f;
#pragma unroll 8
    for (int cc = seg * 64; cc < seg * 64 + 64; ++cc)
        pm += wrow[cc] * Wv[cc * 128 + tt];
    prt[seg][tt] = pm;
    __syncthreads();
    if (t < 128) {
        M16[a * 128 + t] = f2bf(prt[0][t] + prt[1][t]);
        float wo = Wo[a * 128 + t];
        Wo16[a * 128 + t] = f2bf(wo);
        scl[t] = wrow[t] * bvl[t];
        scl2[t] = wo;
    }
    __syncthreads();
    if (t < 64) { scl[t] += scl[t + 64]; scl2[t] += scl2[t + 64]; }
    __syncthreads();
    if (t == 0) {
        float cv = 0.f, wsm = 0.f;
        for (int cc = 0; cc < 64; ++cc) { cv += scl[cc]; wsm += scl2[cc]; }
        cvec[a] = cv; wsum[a] = wsm;
    }
}

// ---------------- pass 2 (bf16 input): per-group double GEMM -> output rows
__global__ __launch_bounds__(256, 2) void k_out16(const unsigned short* __restrict__ x16,
                                                  const unsigned short* __restrict__ M16,
                                                  const unsigned short* __restrict__ Wo16,
                                                  const float* __restrict__ cvec,
                                                  const float* __restrict__ wsum,
                                                  const float* __restrict__ bo,
                                                  float* __restrict__ out, int ngrp) {
    __shared__ short xsk[16384];
    __shared__ float csl[128], wsl[128], bol[128];
    int t = threadIdx.x;
    int l = t & 63, w = t >> 6, hi = l >> 4, c = l & 15;
    int p = blockIdx.x;

    const s16x8* xg = (const s16x8*)(x16 + (size_t)p * 16384);
    s16x8 stg[8];
#pragma unroll
    for (int kk = 0; kk < 8; ++kk) stg[kk] = xg[kk * 256 + t];

    s16x8 bfM[2][4];
#pragma unroll
    for (int rt = 0; rt < 2; ++rt) {
        int r = (2 * w + rt) * 16 + c;
#pragma unroll
        for (int ks = 0; ks < 4; ++ks)
            bfM[rt][ks] = *(const s16x8*)&M16[r * 128 + ks * 32 + hi * 8];
    }
    if (t < 128) { csl[t] = cvec[t]; wsl[t] = wsum[t]; bol[t] = bo[t]; }

#pragma unroll
    for (int kk = 0; kk < 8; ++kk) {
        int ft = kk * 256 + t;
        int j = ft >> 4, d08 = (ft & 15) * 8;
        *(s16x8*)&xsk[j * 128 + (d08 ^ ((j & 7) << 3))] = stg[kk];
    }
    __syncthreads();

    f32x4 acc[8][2] = {};
#pragma unroll
    for (int jt = 0; jt < 8; ++jt) {
        int j = jt * 16 + c;
        s16x8 af[4];
#pragma unroll
        for (int ks = 0; ks < 4; ++ks)
            af[ks] = *(const s16x8*)&xsk[j * 128 + ((ks * 32 + hi * 8) ^ ((j & 7) << 3))];
#pragma unroll
        for (int rt = 0; rt < 2; ++rt)
#pragma unroll
            for (int ks = 0; ks < 4; ++ks)
                acc[jt][rt] = __builtin_amdgcn_mfma_f32_16x16x32_bf16(af[ks], bfM[rt][ks], acc[jt][rt], 0, 0, 0);
    }
    __syncthreads();

#pragma unroll
    for (int jt = 0; jt < 8; ++jt)
#pragma unroll
        for (int rt = 0; rt < 2; ++rt) {
            int r = (2 * w + rt) * 16 + c;
            int j0 = jt * 16 + hi * 4;
            uint64_t pk = 0;
#pragma unroll
            for (int e = 0; e < 4; ++e) pk |= (uint64_t)f2bf(acc[jt][rt][e]) << (16 * e);
            *(uint64_t*)&xsk[r * 128 + (j0 ^ ((r & 7) << 3))] = pk;
        }
    __syncthreads();

    s16x8 bfO[2][4];
#pragma unroll
    for (int ot = 0; ot < 2; ++ot) {
        int o = (2 * w + ot) * 16 + c;
#pragma unroll
        for (int ks = 0; ks < 4; ++ks)
            bfO[ot][ks] = *(const s16x8*)&Wo16[o * 128 + ks * 32 + hi * 8];
    }

    f32x4 acc2[8][2] = {};
#pragma unroll
    for (int rt8 = 0; rt8 < 8; ++rt8) {
        int rr = rt8 * 16 + c;
        s16x8 af[4];
#pragma unroll
        for (int ks = 0; ks < 4; ++ks)
            af[ks] = *(const s16x8*)&xsk[rr * 128 + ((ks * 32 + hi * 8) ^ ((rr & 7) << 3))];
#pragma unroll
        for (int ot = 0; ot < 2; ++ot)
#pragma unroll
            for (int ks = 0; ks < 4; ++ks)
                acc2[rt8][ot] = __builtin_amdgcn_mfma_f32_16x16x32_bf16(af[ks], bfO[ot][ks], acc2[rt8][ot], 0, 0, 0);
    }

#pragma unroll
    for (int rt8 = 0; rt8 < 8; ++rt8)
#pragma unroll
        for (int ot = 0; ot < 2; ++ot)
#pragma unroll
            for (int e = 0; e < 4; ++e) {
                int r = rt8 * 16 + hi * 4 + e;
                int o = (2 * w + ot) * 16 + c;
                float val = acc2[rt8][ot][e] + csl[r] * wsl[o] + bol[o];
                out[((long)r * ngrp + p) * 128 + o] = val;
            }
}

// ---------------- pass 2 (f32 fallback) if workspace too small — r3-style
__global__ __launch_bounds__(256) void k_out32(const float* __restrict__ x,
                                               const unsigned short* __restrict__ M16,
                                               const unsigned short* __restrict__ Wo16,
                                               const float* __restrict__ cvec,
                                               const float* __restrict__ wsum,
                                               const float* __restrict__ bo,
                                               float* __restrict__ out, int ngrp) {
    __shared__ short xsk[16384];
    __shared__ float csl[128], wsl[128], bol[128];
    int t = threadIdx.x;
    int l = t & 63, w = t >> 6, hi = l >> 4, c = l & 15;
    int p = blockIdx.x;

    s16x8 bfM[2][4];
#pragma unroll
    for (int rt = 0; rt < 2; ++rt) {
        int r = (2 * w + rt) * 16 + c;
#pragma unroll
        for (int ks = 0; ks < 4; ++ks)
            bfM[rt][ks] = *(const s16x8*)&M16[r * 128 + ks * 32 + hi * 8];
    }
    if (t < 128) { csl[t] = cvec[t]; wsl[t] = wsum[t]; bol[t] = bo[t]; }

    const fvec4* xg = (const fvec4*)x;
    long xbase = (long)p * 4096;
#pragma unroll 4
    for (int kk = 0; kk < 16; ++kk) {
        int ft = kk * 256 + t;
        fvec4 v = xg[xbase + ft];
        int j = ft >> 5, d0 = (ft & 31) * 4;
        uint64_t pk = 0;
#pragma unroll
        for (int e = 0; e < 4; ++e) pk |= (uint64_t)f2bf(v[e]) << (16 * e);
        *(uint64_t*)&xsk[j * 128 + (d0 ^ ((j & 7) << 3))] = pk;
    }
    __syncthreads();

    f32x4 acc[8][2] = {};
#pragma unroll
    for (int jt = 0; jt < 8; ++jt) {
        int j = jt * 16 + c;
        s16x8 af[4];
#pragma unroll
        for (int ks = 0; ks < 4; ++ks)
            af[ks] = *(const s16x8*)&xsk[j * 128 + ((ks * 32 + hi * 8) ^ ((j & 7) << 3))];
#pragma unroll
        for (int rt = 0; rt < 2; ++rt)
#pragma unroll
            for (int ks = 0; ks < 4; ++ks)
                acc[jt][rt] = __builtin_amdgcn_mfma_f32_16x16x32_bf16(af[ks], bfM[rt][ks], acc[jt][rt], 0, 0, 0);
    }
    __syncthreads();

#pragma unroll
    for (int jt = 0; jt < 8; ++jt)
#pragma unroll
        for (int rt = 0; rt < 2; ++rt) {
            int r = (2 * w + rt) * 16 + c;
            int j0 = jt * 16 + hi * 4;
            uint64_t pk = 0;
#pragma unroll
            for (int e = 0; e < 4; ++e) pk |= (uint64_t)f2bf(acc[jt][rt][e]) << (16 * e);
            *(uint64_t*)&xsk[r * 128 + (j0 ^ ((r & 7) << 3))] = pk;
        }
    __syncthreads();

    s16x8 bfO[2][4];
#pragma unroll
    for (int ot = 0; ot < 2; ++ot) {
        int o = (2 * w + ot) * 16 + c;
#pragma unroll
        for (int ks = 0; ks < 4; ++ks)
            bfO[ot][ks] = *(const s16x8*)&Wo16[o * 128 + ks * 32 + hi * 8];
    }

    f32x4 acc2[8][2] = {};
#pragma unroll
    for (int rt8 = 0; rt8 < 8; ++rt8) {
        int rr = rt8 * 16 + c;
        s16x8 af[4];
#pragma unroll
        for (int ks = 0; ks < 4; ++ks)
            af[ks] = *(const s16x8*)&xsk[rr * 128 + ((ks * 32 + hi * 8) ^ ((rr & 7) << 3))];
#pragma unroll
        for (int ot = 0; ot < 2; ++ot)
#pragma unroll
            for (int ks = 0; ks < 4; ++ks)
                acc2[rt8][ot] = __builtin_amdgcn_mfma_f32_16x16x32_bf16(af[ks], bfO[ot][ks], acc2[rt8][ot], 0, 0, 0);
    }

#pragma unroll
    for (int rt8 = 0; rt8 < 8; ++rt8)
#pragma unroll
        for (int ot = 0; ot < 2; ++ot)
#pragma unroll
            for (int e = 0; e < 4; ++e) {
                int r = rt8 * 16 + hi * 4 + e;
                int o = (2 * w + ot) * 16 + c;
                float val = acc2[rt8][ot][e] + csl[r] * wsl[o] + bol[o];
                out[((long)r * ngrp + p) * 128 + o] = val;
            }
}

// ------------------------------------------------------------------- launcher
extern "C" void kernel_launch(void* const* d_in, const int* in_sizes, int n_in,
                              void* d_out, int out_size, void* d_ws, size_t ws_size,
                              hipStream_t stream) {
    const float* x  = (const float*)d_in[0];
    const float* Wq = (const float*)d_in[1];
    const float* bq = (const float*)d_in[2];
    const float* Wk = (const float*)d_in[3];
    const float* bk = (const float*)d_in[4];
    const float* Wv = (const float*)d_in[5];
    const float* bv = (const float*)d_in[6];
    const float* Wo = (const float*)d_in[7];
    const float* bo = (const float*)d_in[8];
    float* out = (float*)d_out;
    float* ws = (float*)d_ws;

    int Bn   = in_sizes[0] / DD;   // 262144
    int ngrp = Bn / DD;            // 2048

    auto need = [&](int nb1p, bool withX16) -> size_t {
        size_t f = (size_t)nb1p * PART_STRIDE + 16384 + 128 + 128 + 128;
        size_t sh = 2u * 16384 + (withX16 ? (size_t)Bn * DD : 0);
        return f * 4 + sh * 2;
    };

    int nb1; bool useX16;
    if (ws_size >= need(1024, true))      { nb1 = 1024; useX16 = true; }
    else if (ws_size >= need(512, true))  { nb1 = 512;  useX16 = true; }
    else                                  { nb1 = 512;  useX16 = false; }

    float* parts = ws;
    float* G     = ws + (size_t)nb1 * PART_STRIDE;
    float* svec  = G + 16384;
    float* cvec  = svec + 128;
    float* wsumv = cvec + 128;
    unsigned short* M16  = (unsigned short*)(wsumv + 128);
    unsigned short* Wo16 = M16 + 16384;
    unsigned short* x16  = Wo16 + 16384;

    if (useX16) {
        long n8 = (long)Bn * DD / 8;
        int cblocks = (int)(n8 / (256 * 8));  // 2048
        hipLaunchKernelGGL(k_cvt, dim3(cblocks), dim3(256), 0, stream, x, x16);
        hipLaunchKernelGGL(k_gram16, dim3(nb1), dim3(256), 0, stream,
                           x16, ws, Bn / nb1);
    } else {
        hipLaunchKernelGGL(k_gram_f32, dim3(nb1), dim3(256), 0, stream, x, ws);
    }
    hipLaunchKernelGGL(k_reduce, dim3(513), dim3(256), 0, stream,
                       ws, G, svec, nb1);
    hipLaunchKernelGGL(k_mid, dim3(128), dim3(256), 0, stream,
                       G, svec, Wq, bq, Wk, bk, Wv, bv, Wo,
                       M16, Wo16, cvec, wsumv, (float)Bn);
    if (useX16)
        hipLaunchKernelGGL(k_out16, dim3(ngrp), dim3(256), 0, stream,
                           x16, M16, Wo16, cvec, wsumv, bo, out, ngrp);
    else
        hipLaunchKernelGGL(k_out32, dim3(ngrp), dim3(256), 0, stream,
                           x, M16, Wo16, cvec, wsumv, bo, out, ngrp);
}

// Round 13
// 143.322 us; speedup vs baseline: 1.2131x; 1.2131x over previous
//
#include <hip/hip_runtime.h>
#include <stdint.h>

// DenseAttention_61598420959334 — round 13:
//   Model (r12 evidence): our kernels' HBM READS cap ~2.2-2.6 TB/s, WRITES ~7.
//   => minimize read bytes, overlap reads under compute/writes.
//   k_gram : FUSED f32 read -> single-plane bf16 (x16 dump + tr-LDS) ->
//            wave-column-split Gram partials (r12-verified math). 512 blk.
//   k_out16: 2 groups/block, both x16 tiles prefetched at kernel start (T14).
//   k_reduce/k_mid unchanged; r12 fallbacks kept for small-ws.

#define DD 128
#define PART_STRIDE 16512  // 16384 G-partial + 128 s-partial
#define TILE_SH 5184       // shorts per 32x128 tr-subtiled bf16 tile
#define TILE_B  10368
#define GROWS 512          // rows per k_gram block
#define GTILES 16

typedef float f32x4 __attribute__((ext_vector_type(4)));
typedef short s16x8 __attribute__((ext_vector_type(8)));
typedef float fvec4 __attribute__((ext_vector_type(4)));
typedef unsigned int u32x4 __attribute__((ext_vector_type(4)));

__device__ __forceinline__ unsigned short f2bf(float f) {
    union { float f; uint32_t u; } v; v.f = f;
    uint32_t u = v.u;
    u += 0x7FFFu + ((u >> 16) & 1u);
    return (unsigned short)(u >> 16);
}
__device__ __forceinline__ s16x8 mk8(uint64_t lo, uint64_t hi) {
    union { uint64_t u[2]; s16x8 v; } x; x.u[0] = lo; x.u[1] = hi; return x.v;
}

// ------------- k_gram: fused f32 read -> bf16 LDS/x16 -> col-split partials
__global__ __launch_bounds__(256, 2) void k_gram(const float* __restrict__ x,
                                                 float* __restrict__ ws,
                                                 unsigned short* __restrict__ x16) {
    __shared__ __align__(16) short lds[2][TILE_SH];  // 20.7 KB double buffer
    const int t = threadIdx.x;
    const int l = t & 63, w = t >> 6;
    const long rowbase = (long)blockIdx.x * GROWS;

    s16x8 ones;
#pragma unroll
    for (int i = 0; i < 8; ++i) ones[i] = (short)0x3F80;

    f32x4 acc[8][2] = {};   // wave w owns G cols [32w,32w+32)
    f32x4 accs[2] = {};

    const unsigned base0 = (unsigned)(uintptr_t)&lds[0][0];

    // cell geometry (r12-verified): cell idx -> (j row, d0 col-octet)
    const int j0 = t >> 4,        d0a = (t & 15) * 8;
    const int j1 = 16 + (t >> 4);
    const int off0 = 648 * (d0a >> 4) + 320 * ((j0 >> 2) & 1) + 64 * (j0 >> 3) +
                     16 * (j0 & 3) + (d0a & 15);
    const int off1 = 648 * (d0a >> 4) + 320 * ((j1 >> 2) & 1) + 64 * (j1 >> 3) +
                     16 * (j1 & 3) + (d0a & 15);
    const long go0 = (long)j0 * 128 + d0a;
    const long go1 = (long)j1 * 128 + d0a;

    // load 8 f32 per cell, cvt_pk -> 8 bf16, store LDS tr-layout + x16 dump
#define STAGE(BUF, TL) do {                                                     \
        long rb = (rowbase + (long)(TL) * 32) * 128;                            \
        const fvec4* s0 = (const fvec4*)&x[rb + go0];                           \
        const fvec4* s1 = (const fvec4*)&x[rb + go1];                           \
        fvec4 a0 = s0[0], a1 = s0[1];                                           \
        fvec4 b0 = s1[0], b1 = s1[1];                                           \
        uint32_t h0, h1, h2, h3, g0, g1, g2, g3;                                \
        asm("v_cvt_pk_bf16_f32 %0, %1, %2" : "=v"(h0) : "v"(a0[0]), "v"(a0[1])); \
        asm("v_cvt_pk_bf16_f32 %0, %1, %2" : "=v"(h1) : "v"(a0[2]), "v"(a0[3])); \
        asm("v_cvt_pk_bf16_f32 %0, %1, %2" : "=v"(h2) : "v"(a1[0]), "v"(a1[1])); \
        asm("v_cvt_pk_bf16_f32 %0, %1, %2" : "=v"(h3) : "v"(a1[2]), "v"(a1[3])); \
        asm("v_cvt_pk_bf16_f32 %0, %1, %2" : "=v"(g0) : "v"(b0[0]), "v"(b0[1])); \
        asm("v_cvt_pk_bf16_f32 %0, %1, %2" : "=v"(g1) : "v"(b0[2]), "v"(b0[3])); \
        asm("v_cvt_pk_bf16_f32 %0, %1, %2" : "=v"(g2) : "v"(b1[0]), "v"(b1[1])); \
        asm("v_cvt_pk_bf16_f32 %0, %1, %2" : "=v"(g3) : "v"(b1[2]), "v"(b1[3])); \
        u32x4 pa; pa[0] = h0; pa[1] = h1; pa[2] = h2; pa[3] = h3;               \
        u32x4 pb; pb[0] = g0; pb[1] = g1; pb[2] = g2; pb[3] = g3;               \
        *(u32x4*)&lds[BUF][off0] = pa;                                          \
        *(u32x4*)&lds[BUF][off1] = pb;                                          \
        *(u32x4*)&x16[rb + go0] = pa;                                           \
        *(u32x4*)&x16[rb + go1] = pb;                                           \
    } while (0)

    // r12-verified GRAM16: b-frags by wave-uniform address, 16 + 2 MFMA
#define GRAM16(BUF) do {                                                        \
        uint64_t fr[8][2], fbr[2][2];                                           \
        _Pragma("unroll")                                                       \
        for (int a = 0; a < 8; ++a)                                             \
            _Pragma("unroll")                                                   \
            for (int r = 0; r < 2; ++r) {                                       \
                unsigned ad = base0 + (unsigned)((BUF) * TILE_B + a * 1296 +    \
                                                 r * 640) + 8u * (unsigned)l;   \
                asm volatile("ds_read_b64_tr_b16 %0, %1"                        \
                             : "=v"(fr[a][r]) : "v"(ad));                       \
            }                                                                   \
        _Pragma("unroll")                                                       \
        for (int j = 0; j < 2; ++j)                                             \
            _Pragma("unroll")                                                   \
            for (int r = 0; r < 2; ++r) {                                       \
                unsigned ad = base0 + (unsigned)((BUF) * TILE_B + r * 640) +    \
                              1296u * (unsigned)(2 * w + j) + 8u * (unsigned)l; \
                asm volatile("ds_read_b64_tr_b16 %0, %1"                        \
                             : "=v"(fbr[j][r]) : "v"(ad));                      \
            }                                                                   \
        asm volatile("s_waitcnt lgkmcnt(0)" ::: "memory");                      \
        __builtin_amdgcn_sched_barrier(0);                                      \
        s16x8 fg[8], fb[2];                                                     \
        _Pragma("unroll")                                                       \
        for (int a = 0; a < 8; ++a) fg[a] = mk8(fr[a][0], fr[a][1]);            \
        _Pragma("unroll")                                                       \
        for (int j = 0; j < 2; ++j) fb[j] = mk8(fbr[j][0], fbr[j][1]);          \
        _Pragma("unroll")                                                       \
        for (int a = 0; a < 8; ++a)                                             \
            _Pragma("unroll")                                                   \
            for (int j = 0; j < 2; ++j)                                         \
                acc[a][j] = __builtin_amdgcn_mfma_f32_16x16x32_bf16(            \
                    fg[a], fb[j], acc[a][j], 0, 0, 0);                          \
        accs[0] = __builtin_amdgcn_mfma_f32_16x16x32_bf16(ones, fb[0], accs[0], 0, 0, 0); \
        accs[1] = __builtin_amdgcn_mfma_f32_16x16x32_bf16(ones, fb[1], accs[1], 0, 0, 0); \
    } while (0)

    STAGE(0, 0);
    __syncthreads();
#pragma unroll 1
    for (int tl = 0; tl < GTILES; ++tl) {
        if (tl + 1 < GTILES) STAGE((tl + 1) & 1, tl + 1);
        GRAM16(tl & 1);
        __syncthreads();
    }

    // disjoint partial dump (wave-column split; r12-verified)
    long pbase = (long)blockIdx.x * PART_STRIDE;
#pragma unroll
    for (int a = 0; a < 8; ++a)
#pragma unroll
        for (int j = 0; j < 2; ++j)
#pragma unroll
            for (int e = 0; e < 4; ++e) {
                int row = a * 16 + (l >> 4) * 4 + e;
                int col = 32 * w + 16 * j + (l & 15);
                ws[pbase + row * 128 + col] = acc[a][j][e];
            }
    if (l < 16) {
        ws[pbase + 16384 + 32 * w + l]      = accs[0][0];
        ws[pbase + 16384 + 32 * w + 16 + l] = accs[1][0];
    }
#undef STAGE
#undef GRAM16
}

// ---------- fallback gram (f32, r11/r12-verified) if x16 doesn't fit ws
__global__ __launch_bounds__(256) void k_gram_f32(const float* __restrict__ x,
                                                  float* __restrict__ ws) {
    __shared__ __align__(16) unsigned char smem[66048];
    short* tiles = (short*)smem;
    float* grid  = (float*)smem;
    float* sgrid = (float*)(smem + 65536);

    const int t = threadIdx.x;
    const int l = t & 63, w = t >> 6;
    const long rowbase = (long)blockIdx.x * 512 + (long)w * 128;
    const fvec4* xg = (const fvec4*)x;
    short* myt = tiles + w * TILE_SH;
    const unsigned mybase = (unsigned)(uintptr_t)myt;

    f32x4 acc[36] = {};
    float sacc0 = 0.f, sacc1 = 0.f, sacc2 = 0.f, sacc3 = 0.f;
    const int jrow = l >> 5;
    const int cq   = l & 31;

#pragma unroll 1
    for (int tl = 0; tl < 4; ++tl) {
        long r0 = rowbase + tl * 32;
        fvec4 va[8], vb[8];
#pragma unroll
        for (int i = 0; i < 8; ++i) va[i] = xg[(r0 + 2 * i + jrow) * 32 + cq];
#pragma unroll
        for (int i = 0; i < 8; ++i) vb[i] = xg[(r0 + 2 * (i + 8) + jrow) * 32 + cq];

#pragma unroll
        for (int i = 0; i < 16; ++i) {
            fvec4 v = (i < 8) ? va[i & 7] : vb[i & 7];
            int j = 2 * i + jrow;
            int d0 = 4 * cq;
            uint32_t h0, h1;
            asm("v_cvt_pk_bf16_f32 %0, %1, %2" : "=v"(h0) : "v"(v[0]), "v"(v[1]));
            asm("v_cvt_pk_bf16_f32 %0, %1, %2" : "=v"(h1) : "v"(v[2]), "v"(v[3]));
            uint64_t ph = (uint64_t)h0 | ((uint64_t)h1 << 32);
            int off = 648 * (d0 >> 4) + 320 * ((j >> 2) & 1) + 64 * (j >> 3) +
                      16 * (j & 3) + (d0 & 15);
            *(uint64_t*)&myt[off] = ph;
            sacc0 += v[0]; sacc1 += v[1]; sacc2 += v[2]; sacc3 += v[3];
        }
        asm volatile("s_waitcnt lgkmcnt(0)" ::: "memory");
        __builtin_amdgcn_sched_barrier(0);

        uint64_t fr[8][2];
#pragma unroll
        for (int a = 0; a < 8; ++a)
#pragma unroll
            for (int r = 0; r < 2; ++r) {
                unsigned ad = mybase + (unsigned)(a * 1296 + r * 640) + 8u * (unsigned)l;
                asm volatile("ds_read_b64_tr_b16 %0, %1" : "=v"(fr[a][r]) : "v"(ad));
            }
        asm volatile("s_waitcnt lgkmcnt(0)" ::: "memory");
        __builtin_amdgcn_sched_barrier(0);

        s16x8 fg[8];
#pragma unroll
        for (int a = 0; a < 8; ++a) fg[a] = mk8(fr[a][0], fr[a][1]);
        {
            int idx = 0;
#pragma unroll
            for (int a = 0; a < 8; ++a)
#pragma unroll
                for (int b = a; b < 8; ++b) {
                    acc[idx] = __builtin_amdgcn_mfma_f32_16x16x32_bf16(
                        fg[a], fg[b], acc[idx], 0, 0, 0);
                    ++idx;
                }
        }
    }

    sacc0 += __shfl_xor(sacc0, 32);
    sacc1 += __shfl_xor(sacc1, 32);
    sacc2 += __shfl_xor(sacc2, 32);
    sacc3 += __shfl_xor(sacc3, 32);

    __syncthreads();
    for (int ph = 0; ph < 4; ++ph) {
        if (w == ph) {
            int idx = 0;
#pragma unroll
            for (int a = 0; a < 8; ++a)
#pragma unroll
                for (int b = a; b < 8; ++b) {
#pragma unroll
                    for (int e = 0; e < 4; ++e) {
                        int row = a * 16 + (l >> 4) * 4 + e;
                        int col = b * 16 + (l & 15);
                        float val = acc[idx][e];
                        if (ph == 0) {
                            grid[row * 128 + col] = val;
                            if (a != b) grid[col * 128 + row] = val;
                        } else {
                            grid[row * 128 + col] += val;
                            if (a != b) grid[col * 128 + row] += val;
                        }
                    }
                    ++idx;
                }
            if (l < 32) {
                if (ph == 0) {
                    sgrid[4 * l + 0] = sacc0; sgrid[4 * l + 1] = sacc1;
                    sgrid[4 * l + 2] = sacc2; sgrid[4 * l + 3] = sacc3;
                } else {
                    sgrid[4 * l + 0] += sacc0; sgrid[4 * l + 1] += sacc1;
                    sgrid[4 * l + 2] += sacc2; sgrid[4 * l + 3] += sacc3;
                }
            }
        }
        __syncthreads();
    }

    long pbase = (long)blockIdx.x * PART_STRIDE;
    for (int i = t; i < 16384; i += 256) ws[pbase + i] = grid[i];
    if (t < 128) ws[pbase + 16384 + t] = sgrid[t];
}

// ------------------------------------------------------- reduce partials -> G, s
__global__ __launch_bounds__(256) void k_reduce(const float* __restrict__ parts,
                                                float* __restrict__ g_out,
                                                float* __restrict__ s_out, int nb1) {
    __shared__ float red[256];
    int b = blockIdx.x, t = threadIdx.x;
    if (b < 512) {
        int d1 = b >> 2, q = b & 3;
        int c32 = t & 31, pg = t >> 5;
        int per = nb1 >> 3;
        int e = d1 * 128 + q * 32 + c32;
        float acc = 0.f;
#pragma unroll 4
        for (int p = pg * per; p < (pg + 1) * per; ++p)
            acc += parts[(long)p * PART_STRIDE + e];
        red[t] = acc;
        __syncthreads();
        if (pg == 0) {
            float s = red[c32];
#pragma unroll
            for (int k = 1; k < 8; ++k) s += red[k * 32 + c32];
            g_out[e] = s;
        }
    } else {
        int ee = t & 127, hg = t >> 7;
        int per = nb1 >> 1;
        float acc = 0.f;
#pragma unroll 4
        for (int p = hg * per; p < (hg + 1) * per; ++p)
            acc += parts[(long)p * PART_STRIDE + 16384 + ee];
        red[t] = acc;
        __syncthreads();
        if (hg == 0) s_out[ee] = red[ee] + red[128 + ee];
    }
}

// ---- k_mid: scores row a from G (in LDS) + softmax + M row + c/wsum + casts
__global__ __launch_bounds__(256) void k_mid(const float* __restrict__ G,
                                             const float* __restrict__ s,
                                             const float* __restrict__ Wq,
                                             const float* __restrict__ bq,
                                             const float* __restrict__ Wk,
                                             const float* __restrict__ bk,
                                             const float* __restrict__ Wv,
                                             const float* __restrict__ bv,
                                             const float* __restrict__ Wo,
                                             unsigned short* __restrict__ M16,
                                             unsigned short* __restrict__ Wo16,
                                             float* __restrict__ cvec,
                                             float* __restrict__ wsum, float Bn) {
    __shared__ float gl[16384];
    __shared__ float wk[128 * 129];
    __shared__ float wqr[128], sl[128], bkl[128], bvl[128];
    __shared__ float prt[2][128], prt2[2][128];
    __shared__ float tmp[128], scl[128], wrow[128], scl2[128];
    int t = threadIdx.x, a = blockIdx.x;
    int tt = t & 127, seg = t >> 7;

    {
        const fvec4* gg = (const fvec4*)G;
        fvec4* gs = (fvec4*)gl;
        for (int i = t; i < 4096; i += 256) gs[i] = gg[i];
    }
    for (int idx = t; idx < 16384; idx += 256) {
        int r = idx >> 7, cc = idx & 127;
        wk[r * 129 + cc] = Wk[idx];
    }
    if (t < 128) {
        wqr[t] = Wq[a * 128 + t];
        sl[t] = s[t]; bkl[t] = bk[t]; bvl[t] = bv[t];
    }
    __syncthreads();

    float tm = 0.f;
#pragma unroll 8
    for (int d1 = seg * 64; d1 < seg * 64 + 64; ++d1) tm += wqr[d1] * gl[d1 * 128 + tt];
    prt[seg][tt] = tm;
    __syncthreads();
    if (t < 128) tmp[t] = prt[0][t] + prt[1][t];
    __syncthreads();

    float p1 = 0.f, p2 = 0.f;
#pragma unroll 8
    for (int d = seg * 64; d < seg * 64 + 64; ++d) {
        float w2 = wk[tt * 129 + d];
        p1 += tmp[d] * w2;
        p2 += sl[d] * w2;
    }
    prt[seg][tt] = p1;
    prt2[seg][tt] = p2;
    __syncthreads();
    if (t < 128) {
        float tdot = prt[0][t] + prt[1][t];
        float kdot = prt2[0][t] + prt2[1][t];
        float qs = 0.f;
#pragma unroll 8
        for (int d = 0; d < 128; ++d) qs += wqr[d] * sl[d];
        float bqa = bq[a];
        float sc = (tdot + qs * bkl[t] + bqa * kdot + Bn * bqa * bkl[t]) *
                   0.0883883476483184406f;
        scl[t] = sc;
    }
    __syncthreads();
    if (t < 128) {
        float mx = -1e30f;
        for (int i2 = 0; i2 < 128; ++i2) mx = fmaxf(mx, scl[i2]);
        scl2[t] = expf(scl[t] - mx);
    }
    __syncthreads();
    if (t < 128) {
        float sum = 0.f;
        for (int i2 = 0; i2 < 128; ++i2) sum += scl2[i2];
        wrow[t] = scl2[t] / sum;
    }
    __syncthreads();

    float pm = 0.f;
#pragma unroll 8
    for (int cc = seg * 64; cc < seg * 64 + 64; ++cc)
        pm += wrow[cc] * Wv[cc * 128 + tt];
    prt[seg][tt] = pm;
    __syncthreads();
    if (t < 128) {
        M16[a * 128 + t] = f2bf(prt[0][t] + prt[1][t]);
        float wo = Wo[a * 128 + t];
        Wo16[a * 128 + t] = f2bf(wo);
        scl[t] = wrow[t] * bvl[t];
        scl2[t] = wo;
    }
    __syncthreads();
    if (t < 64) { scl[t] += scl[t + 64]; scl2[t] += scl2[t + 64]; }
    __syncthreads();
    if (t == 0) {
        float cv = 0.f, wsm = 0.f;
        for (int cc = 0; cc < 64; ++cc) { cv += scl[cc]; wsm += scl2[cc]; }
        cvec[a] = cv; wsum[a] = wsm;
    }
}

// -------- pass 2 (bf16): 2 groups/block, both tiles prefetched (T14)
__global__ __launch_bounds__(256, 2) void k_out16(const unsigned short* __restrict__ x16,
                                                  const unsigned short* __restrict__ M16,
                                                  const unsigned short* __restrict__ Wo16,
                                                  const float* __restrict__ cvec,
                                                  const float* __restrict__ wsum,
                                                  const float* __restrict__ bo,
                                                  float* __restrict__ out,
                                                  int ngrp, int npb) {
    __shared__ short xsk[16384];
    __shared__ float csl[128], wsl[128], bol[128];
    int t = threadIdx.x;
    int l = t & 63, w = t >> 6, hi = l >> 4, c = l & 15;
    int p0 = blockIdx.x;

    // prefetch BOTH groups' x16 tiles up front (reads overlap group-A compute)
    const s16x8* xgA = (const s16x8*)(x16 + (size_t)p0 * 16384);
    const s16x8* xgB = (const s16x8*)(x16 + (size_t)(p0 + npb) * 16384);
    s16x8 stgA[8], stgB[8];
#pragma unroll
    for (int kk = 0; kk < 8; ++kk) stgA[kk] = xgA[kk * 256 + t];
#pragma unroll
    for (int kk = 0; kk < 8; ++kk) stgB[kk] = xgB[kk * 256 + t];

    s16x8 bfM[2][4], bfO[2][4];
#pragma unroll
    for (int rt = 0; rt < 2; ++rt) {
        int r = (2 * w + rt) * 16 + c;
#pragma unroll
        for (int ks = 0; ks < 4; ++ks) {
            bfM[rt][ks] = *(const s16x8*)&M16[r * 128 + ks * 32 + hi * 8];
            bfO[rt][ks] = *(const s16x8*)&Wo16[r * 128 + ks * 32 + hi * 8];
        }
    }
    if (t < 128) { csl[t] = cvec[t]; wsl[t] = wsum[t]; bol[t] = bo[t]; }

#define OUTGROUP(STG, P) do {                                                   \
        _Pragma("unroll")                                                       \
        for (int kk = 0; kk < 8; ++kk) {                                        \
            int ft = kk * 256 + t;                                              \
            int j = ft >> 4, d08 = (ft & 15) * 8;                               \
            *(s16x8*)&xsk[j * 128 + (d08 ^ ((j & 7) << 3))] = STG[kk];          \
        }                                                                       \
        __syncthreads();                                                        \
        f32x4 acc[8][2] = {};                                                   \
        _Pragma("unroll")                                                       \
        for (int jt = 0; jt < 8; ++jt) {                                        \
            int j = jt * 16 + c;                                                \
            s16x8 af[4];                                                        \
            _Pragma("unroll")                                                   \
            for (int ks = 0; ks < 4; ++ks)                                      \
                af[ks] = *(const s16x8*)&xsk[j * 128 + ((ks * 32 + hi * 8) ^ ((j & 7) << 3))]; \
            _Pragma("unroll")                                                   \
            for (int rt = 0; rt < 2; ++rt)                                      \
                _Pragma("unroll")                                               \
                for (int ks = 0; ks < 4; ++ks)                                  \
                    acc[jt][rt] = __builtin_amdgcn_mfma_f32_16x16x32_bf16(af[ks], bfM[rt][ks], acc[jt][rt], 0, 0, 0); \
        }                                                                       \
        __syncthreads();                                                        \
        _Pragma("unroll")                                                       \
        for (int jt = 0; jt < 8; ++jt)                                          \
            _Pragma("unroll")                                                   \
            for (int rt = 0; rt < 2; ++rt) {                                    \
                int r = (2 * w + rt) * 16 + c;                                  \
                int j0 = jt * 16 + hi * 4;                                      \
                uint64_t pk = 0;                                                \
                _Pragma("unroll")                                               \
                for (int e = 0; e < 4; ++e) pk |= (uint64_t)f2bf(acc[jt][rt][e]) << (16 * e); \
                *(uint64_t*)&xsk[r * 128 + (j0 ^ ((r & 7) << 3))] = pk;         \
            }                                                                   \
        __syncthreads();                                                        \
        f32x4 acc2[8][2] = {};                                                  \
        _Pragma("unroll")                                                       \
        for (int rt8 = 0; rt8 < 8; ++rt8) {                                     \
            int rr = rt8 * 16 + c;                                              \
            s16x8 af[4];                                                        \
            _Pragma("unroll")                                                   \
            for (int ks = 0; ks < 4; ++ks)                                      \
                af[ks] = *(const s16x8*)&xsk[rr * 128 + ((ks * 32 + hi * 8) ^ ((rr & 7) << 3))]; \
            _Pragma("unroll")                                                   \
            for (int ot = 0; ot < 2; ++ot)                                      \
                _Pragma("unroll")                                               \
                for (int ks = 0; ks < 4; ++ks)                                  \
                    acc2[rt8][ot] = __builtin_amdgcn_mfma_f32_16x16x32_bf16(af[ks], bfO[ot][ks], acc2[rt8][ot], 0, 0, 0); \
        }                                                                       \
        _Pragma("unroll")                                                       \
        for (int rt8 = 0; rt8 < 8; ++rt8)                                       \
            _Pragma("unroll")                                                   \
            for (int ot = 0; ot < 2; ++ot)                                      \
                _Pragma("unroll")                                               \
                for (int e = 0; e < 4; ++e) {                                   \
                    int r = rt8 * 16 + hi * 4 + e;                              \
                    int o = (2 * w + ot) * 16 + c;                              \
                    float val = acc2[rt8][ot][e] + csl[r] * wsl[o] + bol[o];    \
                    out[((long)r * ngrp + (P)) * 128 + o] = val;                \
                }                                                               \
        __syncthreads();                                                        \
    } while (0)

    OUTGROUP(stgA, p0);
    OUTGROUP(stgB, p0 + npb);
#undef OUTGROUP
}

// ---------------- pass 2 (f32 fallback) if workspace too small — r3-style
__global__ __launch_bounds__(256) void k_out32(const float* __restrict__ x,
                                               const unsigned short* __restrict__ M16,
                                               const unsigned short* __restrict__ Wo16,
                                               const float* __restrict__ cvec,
                                               const float* __restrict__ wsum,
                                               const float* __restrict__ bo,
                                               float* __restrict__ out, int ngrp) {
    __shared__ short xsk[16384];
    __shared__ float csl[128], wsl[128], bol[128];
    int t = threadIdx.x;
    int l = t & 63, w = t >> 6, hi = l >> 4, c = l & 15;
    int p = blockIdx.x;

    s16x8 bfM[2][4];
#pragma unroll
    for (int rt = 0; rt < 2; ++rt) {
        int r = (2 * w + rt) * 16 + c;
#pragma unroll
        for (int ks = 0; ks < 4; ++ks)
            bfM[rt][ks] = *(const s16x8*)&M16[r * 128 + ks * 32 + hi * 8];
    }
    if (t < 128) { csl[t] = cvec[t]; wsl[t] = wsum[t]; bol[t] = bo[t]; }

    const fvec4* xg = (const fvec4*)x;
    long xbase = (long)p * 4096;
#pragma unroll 4
    for (int kk = 0; kk < 16; ++kk) {
        int ft = kk * 256 + t;
        fvec4 v = xg[xbase + ft];
        int j = ft >> 5, d0 = (ft & 31) * 4;
        uint64_t pk = 0;
#pragma unroll
        for (int e = 0; e < 4; ++e) pk |= (uint64_t)f2bf(v[e]) << (16 * e);
        *(uint64_t*)&xsk[j * 128 + (d0 ^ ((j & 7) << 3))] = pk;
    }
    __syncthreads();

    f32x4 acc[8][2] = {};
#pragma unroll
    for (int jt = 0; jt < 8; ++jt) {
        int j = jt * 16 + c;
        s16x8 af[4];
#pragma unroll
        for (int ks = 0; ks < 4; ++ks)
            af[ks] = *(const s16x8*)&xsk[j * 128 + ((ks * 32 + hi * 8) ^ ((j & 7) << 3))];
#pragma unroll
        for (int rt = 0; rt < 2; ++rt)
#pragma unroll
            for (int ks = 0; ks < 4; ++ks)
                acc[jt][rt] = __builtin_amdgcn_mfma_f32_16x16x32_bf16(af[ks], bfM[rt][ks], acc[jt][rt], 0, 0, 0);
    }
    __syncthreads();

#pragma unroll
    for (int jt = 0; jt < 8; ++jt)
#pragma unroll
        for (int rt = 0; rt < 2; ++rt) {
            int r = (2 * w + rt) * 16 + c;
            int j0 = jt * 16 + hi * 4;
            uint64_t pk = 0;
#pragma unroll
            for (int e = 0; e < 4; ++e) pk |= (uint64_t)f2bf(acc[jt][rt][e]) << (16 * e);
            *(uint64_t*)&xsk[r * 128 + (j0 ^ ((r & 7) << 3))] = pk;
        }
    __syncthreads();

    s16x8 bfO[2][4];
#pragma unroll
    for (int ot = 0; ot < 2; ++ot) {
        int o = (2 * w + ot) * 16 + c;
#pragma unroll
        for (int ks = 0; ks < 4; ++ks)
            bfO[ot][ks] = *(const s16x8*)&Wo16[o * 128 + ks * 32 + hi * 8];
    }

    f32x4 acc2[8][2] = {};
#pragma unroll
    for (int rt8 = 0; rt8 < 8; ++rt8) {
        int rr = rt8 * 16 + c;
        s16x8 af[4];
#pragma unroll
        for (int ks = 0; ks < 4; ++ks)
            af[ks] = *(const s16x8*)&xsk[rr * 128 + ((ks * 32 + hi * 8) ^ ((rr & 7) << 3))];
#pragma unroll
        for (int ot = 0; ot < 2; ++ot)
#pragma unroll
            for (int ks = 0; ks < 4; ++ks)
                acc2[rt8][ot] = __builtin_amdgcn_mfma_f32_16x16x32_bf16(af[ks], bfO[ot][ks], acc2[rt8][ot], 0, 0, 0);
    }

#pragma unroll
    for (int rt8 = 0; rt8 < 8; ++rt8)
#pragma unroll
        for (int ot = 0; ot < 2; ++ot)
#pragma unroll
            for (int e = 0; e < 4; ++e) {
                int r = rt8 * 16 + hi * 4 + e;
                int o = (2 * w + ot) * 16 + c;
                float val = acc2[rt8][ot][e] + csl[r] * wsl[o] + bol[o];
                out[((long)r * ngrp + p) * 128 + o] = val;
            }
}

// ------------------------------------------------------------------- launcher
extern "C" void kernel_launch(void* const* d_in, const int* in_sizes, int n_in,
                              void* d_out, int out_size, void* d_ws, size_t ws_size,
                              hipStream_t stream) {
    const float* x  = (const float*)d_in[0];
    const float* Wq = (const float*)d_in[1];
    const float* bq = (const float*)d_in[2];
    const float* Wk = (const float*)d_in[3];
    const float* bk = (const float*)d_in[4];
    const float* Wv = (const float*)d_in[5];
    const float* bv = (const float*)d_in[6];
    const float* Wo = (const float*)d_in[7];
    const float* bo = (const float*)d_in[8];
    float* out = (float*)d_out;
    float* ws = (float*)d_ws;

    int Bn   = in_sizes[0] / DD;   // 262144
    int ngrp = Bn / DD;            // 2048
    int nb1  = Bn / GROWS;         // 512

    size_t floats = (size_t)nb1 * PART_STRIDE + 16384 + 128 + 128 + 128;
    size_t needed = floats * 4 + (size_t)2 * 16384 * 2 + (size_t)Bn * DD * 2;
    bool use16 = ws_size >= needed;

    float* parts = ws;
    float* G     = ws + (size_t)nb1 * PART_STRIDE;
    float* svec  = G + 16384;
    float* cvec  = svec + 128;
    float* wsumv = cvec + 128;
    unsigned short* M16  = (unsigned short*)(wsumv + 128);
    unsigned short* Wo16 = M16 + 16384;
    unsigned short* x16  = Wo16 + 16384;

    if (use16)
        hipLaunchKernelGGL(k_gram, dim3(nb1), dim3(256), 0, stream, x, ws, x16);
    else
        hipLaunchKernelGGL(k_gram_f32, dim3(nb1), dim3(256), 0, stream, x, ws);
    hipLaunchKernelGGL(k_reduce, dim3(513), dim3(256), 0, stream,
                       ws, G, svec, nb1);
    hipLaunchKernelGGL(k_mid, dim3(128), dim3(256), 0, stream,
                       G, svec, Wq, bq, Wk, bk, Wv, bv, Wo,
                       M16, Wo16, cvec, wsumv, (float)Bn);
    if (use16)
        hipLaunchKernelGGL(k_out16, dim3(ngrp / 2), dim3(256), 0, stream,
                           x16, M16, Wo16, cvec, wsumv, bo, out, ngrp, ngrp / 2);
    else
        hipLaunchKernelGGL(k_out32, dim3(ngrp), dim3(256), 0, stream,
                           x, M16, Wo16, cvec, wsumv, bo, out, ngrp);
}

// Round 14
// 115.875 us; speedup vs baseline: 1.5004x; 1.2369x over previous
//
#include <hip/hip_runtime.h>
#include <stdint.h>

// DenseAttention_61598420959334 — round 14: minimum-traffic assembly.
//   Evidence: any x-reading kernel runs ~65-76us regardless of structure
//   (r5-r13); the only sub-135 total ever timed was r9's plan (no x16 dump,
//   f32 L3-resident re-read in pass 2). Rebuild that plan race-free:
//   k_gram : fused f32->bf16 single-plane gram (r13 math), NO x16 dump,
//            1024 rows/block (256 blocks, partials 16.9 MB)
//   k_reduce: nb1=256
//   k_mid  : unchanged (r13)
//   k_out32: f32 re-read (L3-hot), r3-validated double GEMM

#define DD 128
#define PART_STRIDE 16512  // 16384 G-partial + 128 s-partial
#define TILE_SH 5184       // shorts per 32x128 tr-subtiled bf16 tile
#define TILE_B  10368
#define GROWS 1024         // rows per k_gram block
#define GTILES 32

typedef float f32x4 __attribute__((ext_vector_type(4)));
typedef short s16x8 __attribute__((ext_vector_type(8)));
typedef float fvec4 __attribute__((ext_vector_type(4)));
typedef unsigned int u32x4 __attribute__((ext_vector_type(4)));

__device__ __forceinline__ unsigned short f2bf(float f) {
    union { float f; uint32_t u; } v; v.f = f;
    uint32_t u = v.u;
    u += 0x7FFFu + ((u >> 16) & 1u);
    return (unsigned short)(u >> 16);
}
__device__ __forceinline__ s16x8 mk8(uint64_t lo, uint64_t hi) {
    union { uint64_t u[2]; s16x8 v; } x; x.u[0] = lo; x.u[1] = hi; return x.v;
}

// ------------- k_gram: fused f32 read -> bf16 LDS -> col-split partials
__global__ __launch_bounds__(256, 2) void k_gram(const float* __restrict__ x,
                                                 float* __restrict__ ws) {
    __shared__ __align__(16) short lds[2][TILE_SH];  // 20.7 KB double buffer
    const int t = threadIdx.x;
    const int l = t & 63, w = t >> 6;
    const long rowbase = (long)blockIdx.x * GROWS;

    s16x8 ones;
#pragma unroll
    for (int i = 0; i < 8; ++i) ones[i] = (short)0x3F80;

    f32x4 acc[8][2] = {};   // wave w owns G cols [32w,32w+32)
    f32x4 accs[2] = {};

    const unsigned base0 = (unsigned)(uintptr_t)&lds[0][0];

    // cell geometry (r12/r13-verified): cell idx -> (j row, d0 col-octet)
    const int j0 = t >> 4,        d0a = (t & 15) * 8;
    const int j1 = 16 + (t >> 4);
    const int off0 = 648 * (d0a >> 4) + 320 * ((j0 >> 2) & 1) + 64 * (j0 >> 3) +
                     16 * (j0 & 3) + (d0a & 15);
    const int off1 = 648 * (d0a >> 4) + 320 * ((j1 >> 2) & 1) + 64 * (j1 >> 3) +
                     16 * (j1 & 3) + (d0a & 15);
    const long go0 = (long)j0 * 128 + d0a;
    const long go1 = (long)j1 * 128 + d0a;

#define STAGE(BUF, TL) do {                                                     \
        long rb = (rowbase + (long)(TL) * 32) * 128;                            \
        const fvec4* s0 = (const fvec4*)&x[rb + go0];                           \
        const fvec4* s1 = (const fvec4*)&x[rb + go1];                           \
        fvec4 a0 = s0[0], a1 = s0[1];                                           \
        fvec4 b0 = s1[0], b1 = s1[1];                                           \
        uint32_t h0, h1, h2, h3, g0, g1, g2, g3;                                \
        asm("v_cvt_pk_bf16_f32 %0, %1, %2" : "=v"(h0) : "v"(a0[0]), "v"(a0[1])); \
        asm("v_cvt_pk_bf16_f32 %0, %1, %2" : "=v"(h1) : "v"(a0[2]), "v"(a0[3])); \
        asm("v_cvt_pk_bf16_f32 %0, %1, %2" : "=v"(h2) : "v"(a1[0]), "v"(a1[1])); \
        asm("v_cvt_pk_bf16_f32 %0, %1, %2" : "=v"(h3) : "v"(a1[2]), "v"(a1[3])); \
        asm("v_cvt_pk_bf16_f32 %0, %1, %2" : "=v"(g0) : "v"(b0[0]), "v"(b0[1])); \
        asm("v_cvt_pk_bf16_f32 %0, %1, %2" : "=v"(g1) : "v"(b0[2]), "v"(b0[3])); \
        asm("v_cvt_pk_bf16_f32 %0, %1, %2" : "=v"(g2) : "v"(b1[0]), "v"(b1[1])); \
        asm("v_cvt_pk_bf16_f32 %0, %1, %2" : "=v"(g3) : "v"(b1[2]), "v"(b1[3])); \
        u32x4 pa; pa[0] = h0; pa[1] = h1; pa[2] = h2; pa[3] = h3;               \
        u32x4 pb; pb[0] = g0; pb[1] = g1; pb[2] = g2; pb[3] = g3;               \
        *(u32x4*)&lds[BUF][off0] = pa;                                          \
        *(u32x4*)&lds[BUF][off1] = pb;                                          \
    } while (0)

    // r12/r13-verified GRAM16: b-frags by wave-uniform address, 16 + 2 MFMA
#define GRAM16(BUF) do {                                                        \
        uint64_t fr[8][2], fbr[2][2];                                           \
        _Pragma("unroll")                                                       \
        for (int a = 0; a < 8; ++a)                                             \
            _Pragma("unroll")                                                   \
            for (int r = 0; r < 2; ++r) {                                       \
                unsigned ad = base0 + (unsigned)((BUF) * TILE_B + a * 1296 +    \
                                                 r * 640) + 8u * (unsigned)l;   \
                asm volatile("ds_read_b64_tr_b16 %0, %1"                        \
                             : "=v"(fr[a][r]) : "v"(ad));                       \
            }                                                                   \
        _Pragma("unroll")                                                       \
        for (int j = 0; j < 2; ++j)                                             \
            _Pragma("unroll")                                                   \
            for (int r = 0; r < 2; ++r) {                                       \
                unsigned ad = base0 + (unsigned)((BUF) * TILE_B + r * 640) +    \
                              1296u * (unsigned)(2 * w + j) + 8u * (unsigned)l; \
                asm volatile("ds_read_b64_tr_b16 %0, %1"                        \
                             : "=v"(fbr[j][r]) : "v"(ad));                      \
            }                                                                   \
        asm volatile("s_waitcnt lgkmcnt(0)" ::: "memory");                      \
        __builtin_amdgcn_sched_barrier(0);                                      \
        s16x8 fg[8], fb[2];                                                     \
        _Pragma("unroll")                                                       \
        for (int a = 0; a < 8; ++a) fg[a] = mk8(fr[a][0], fr[a][1]);            \
        _Pragma("unroll")                                                       \
        for (int j = 0; j < 2; ++j) fb[j] = mk8(fbr[j][0], fbr[j][1]);          \
        _Pragma("unroll")                                                       \
        for (int a = 0; a < 8; ++a)                                             \
            _Pragma("unroll")                                                   \
            for (int j = 0; j < 2; ++j)                                         \
                acc[a][j] = __builtin_amdgcn_mfma_f32_16x16x32_bf16(            \
                    fg[a], fb[j], acc[a][j], 0, 0, 0);                          \
        accs[0] = __builtin_amdgcn_mfma_f32_16x16x32_bf16(ones, fb[0], accs[0], 0, 0, 0); \
        accs[1] = __builtin_amdgcn_mfma_f32_16x16x32_bf16(ones, fb[1], accs[1], 0, 0, 0); \
    } while (0)

    STAGE(0, 0);
    __syncthreads();
#pragma unroll 1
    for (int tl = 0; tl < GTILES; ++tl) {
        if (tl + 1 < GTILES) STAGE((tl + 1) & 1, tl + 1);
        GRAM16(tl & 1);
        __syncthreads();
    }

    // disjoint partial dump (wave-column split; r12/r13-verified)
    long pbase = (long)blockIdx.x * PART_STRIDE;
#pragma unroll
    for (int a = 0; a < 8; ++a)
#pragma unroll
        for (int j = 0; j < 2; ++j)
#pragma unroll
            for (int e = 0; e < 4; ++e) {
                int row = a * 16 + (l >> 4) * 4 + e;
                int col = 32 * w + 16 * j + (l & 15);
                ws[pbase + row * 128 + col] = acc[a][j][e];
            }
    if (l < 16) {
        ws[pbase + 16384 + 32 * w + l]      = accs[0][0];
        ws[pbase + 16384 + 32 * w + 16 + l] = accs[1][0];
    }
#undef STAGE
#undef GRAM16
}

// ------------------------------------------------------- reduce partials -> G, s
__global__ __launch_bounds__(256) void k_reduce(const float* __restrict__ parts,
                                                float* __restrict__ g_out,
                                                float* __restrict__ s_out, int nb1) {
    __shared__ float red[256];
    int b = blockIdx.x, t = threadIdx.x;
    if (b < 512) {
        int d1 = b >> 2, q = b & 3;
        int c32 = t & 31, pg = t >> 5;
        int per = nb1 >> 3;
        int e = d1 * 128 + q * 32 + c32;
        float acc = 0.f;
#pragma unroll 4
        for (int p = pg * per; p < (pg + 1) * per; ++p)
            acc += parts[(long)p * PART_STRIDE + e];
        red[t] = acc;
        __syncthreads();
        if (pg == 0) {
            float s = red[c32];
#pragma unroll
            for (int k = 1; k < 8; ++k) s += red[k * 32 + c32];
            g_out[e] = s;
        }
    } else {
        int ee = t & 127, hg = t >> 7;
        int per = nb1 >> 1;
        float acc = 0.f;
#pragma unroll 4
        for (int p = hg * per; p < (hg + 1) * per; ++p)
            acc += parts[(long)p * PART_STRIDE + 16384 + ee];
        red[t] = acc;
        __syncthreads();
        if (hg == 0) s_out[ee] = red[ee] + red[128 + ee];
    }
}

// ---- k_mid: scores row a from G (in LDS) + softmax + M row + c/wsum + casts
__global__ __launch_bounds__(256) void k_mid(const float* __restrict__ G,
                                             const float* __restrict__ s,
                                             const float* __restrict__ Wq,
                                             const float* __restrict__ bq,
                                             const float* __restrict__ Wk,
                                             const float* __restrict__ bk,
                                             const float* __restrict__ Wv,
                                             const float* __restrict__ bv,
                                             const float* __restrict__ Wo,
                                             unsigned short* __restrict__ M16,
                                             unsigned short* __restrict__ Wo16,
                                             float* __restrict__ cvec,
                                             float* __restrict__ wsum, float Bn) {
    __shared__ float gl[16384];
    __shared__ float wk[128 * 129];
    __shared__ float wqr[128], sl[128], bkl[128], bvl[128];
    __shared__ float prt[2][128], prt2[2][128];
    __shared__ float tmp[128], scl[128], wrow[128], scl2[128];
    int t = threadIdx.x, a = blockIdx.x;
    int tt = t & 127, seg = t >> 7;

    {
        const fvec4* gg = (const fvec4*)G;
        fvec4* gs = (fvec4*)gl;
        for (int i = t; i < 4096; i += 256) gs[i] = gg[i];
    }
    for (int idx = t; idx < 16384; idx += 256) {
        int r = idx >> 7, cc = idx & 127;
        wk[r * 129 + cc] = Wk[idx];
    }
    if (t < 128) {
        wqr[t] = Wq[a * 128 + t];
        sl[t] = s[t]; bkl[t] = bk[t]; bvl[t] = bv[t];
    }
    __syncthreads();

    float tm = 0.f;
#pragma unroll 8
    for (int d1 = seg * 64; d1 < seg * 64 + 64; ++d1) tm += wqr[d1] * gl[d1 * 128 + tt];
    prt[seg][tt] = tm;
    __syncthreads();
    if (t < 128) tmp[t] = prt[0][t] + prt[1][t];
    __syncthreads();

    float p1 = 0.f, p2 = 0.f;
#pragma unroll 8
    for (int d = seg * 64; d < seg * 64 + 64; ++d) {
        float w2 = wk[tt * 129 + d];
        p1 += tmp[d] * w2;
        p2 += sl[d] * w2;
    }
    prt[seg][tt] = p1;
    prt2[seg][tt] = p2;
    __syncthreads();
    if (t < 128) {
        float tdot = prt[0][t] + prt[1][t];
        float kdot = prt2[0][t] + prt2[1][t];
        float qs = 0.f;
#pragma unroll 8
        for (int d = 0; d < 128; ++d) qs += wqr[d] * sl[d];
        float bqa = bq[a];
        float sc = (tdot + qs * bkl[t] + bqa * kdot + Bn * bqa * bkl[t]) *
                   0.0883883476483184406f;
        scl[t] = sc;
    }
    __syncthreads();
    if (t < 128) {
        float mx = -1e30f;
        for (int i2 = 0; i2 < 128; ++i2) mx = fmaxf(mx, scl[i2]);
        scl2[t] = expf(scl[t] - mx);
    }
    __syncthreads();
    if (t < 128) {
        float sum = 0.f;
        for (int i2 = 0; i2 < 128; ++i2) sum += scl2[i2];
        wrow[t] = scl2[t] / sum;
    }
    __syncthreads();

    float pm = 0.f;
#pragma unroll 8
    for (int cc = seg * 64; cc < seg * 64 + 64; ++cc)
        pm += wrow[cc] * Wv[cc * 128 + tt];
    prt[seg][tt] = pm;
    __syncthreads();
    if (t < 128) {
        M16[a * 128 + t] = f2bf(prt[0][t] + prt[1][t]);
        float wo = Wo[a * 128 + t];
        Wo16[a * 128 + t] = f2bf(wo);
        scl[t] = wrow[t] * bvl[t];
        scl2[t] = wo;
    }
    __syncthreads();
    if (t < 64) { scl[t] += scl[t + 64]; scl2[t] += scl2[t + 64]; }
    __syncthreads();
    if (t == 0) {
        float cv = 0.f, wsm = 0.f;
        for (int cc = 0; cc < 64; ++cc) { cv += scl[cc]; wsm += scl2[cc]; }
        cvec[a] = cv; wsum[a] = wsm;
    }
}

// -------- pass 2: per-group double GEMM, f32 x re-read (L3-hot) — r3-validated
__global__ __launch_bounds__(256) void k_out32(const float* __restrict__ x,
                                               const unsigned short* __restrict__ M16,
                                               const unsigned short* __restrict__ Wo16,
                                               const float* __restrict__ cvec,
                                               const float* __restrict__ wsum,
                                               const float* __restrict__ bo,
                                               float* __restrict__ out, int ngrp) {
    __shared__ short xsk[16384];  // X_p bf16 swizzled; reused as U^T after GEMM1
    __shared__ float csl[128], wsl[128], bol[128];
    int t = threadIdx.x;
    int l = t & 63, w = t >> 6, hi = l >> 4, c = l & 15;
    int p = blockIdx.x;

    s16x8 bfM[2][4];
#pragma unroll
    for (int rt = 0; rt < 2; ++rt) {
        int r = (2 * w + rt) * 16 + c;
#pragma unroll
        for (int ks = 0; ks < 4; ++ks)
            bfM[rt][ks] = *(const s16x8*)&M16[r * 128 + ks * 32 + hi * 8];
    }
    if (t < 128) { csl[t] = cvec[t]; wsl[t] = wsum[t]; bol[t] = bo[t]; }

    const fvec4* xg = (const fvec4*)x;
    long xbase = (long)p * 4096;
#pragma unroll 4
    for (int kk = 0; kk < 16; ++kk) {
        int ft = kk * 256 + t;
        fvec4 v = xg[xbase + ft];
        int j = ft >> 5, d0 = (ft & 31) * 4;
        uint64_t pk = 0;
#pragma unroll
        for (int e = 0; e < 4; ++e) pk |= (uint64_t)f2bf(v[e]) << (16 * e);
        *(uint64_t*)&xsk[j * 128 + (d0 ^ ((j & 7) << 3))] = pk;
    }
    __syncthreads();

    // GEMM1: U[j][r] = sum_d X[j,d] M[r,d]
    f32x4 acc[8][2] = {};
#pragma unroll
    for (int jt = 0; jt < 8; ++jt) {
        int j = jt * 16 + c;
        s16x8 af[4];
#pragma unroll
        for (int ks = 0; ks < 4; ++ks)
            af[ks] = *(const s16x8*)&xsk[j * 128 + ((ks * 32 + hi * 8) ^ ((j & 7) << 3))];
#pragma unroll
        for (int rt = 0; rt < 2; ++rt)
#pragma unroll
            for (int ks = 0; ks < 4; ++ks)
                acc[jt][rt] = __builtin_amdgcn_mfma_f32_16x16x32_bf16(af[ks], bfM[rt][ks], acc[jt][rt], 0, 0, 0);
    }
    __syncthreads();

    // write U^T into the same buffer
#pragma unroll
    for (int jt = 0; jt < 8; ++jt)
#pragma unroll
        for (int rt = 0; rt < 2; ++rt) {
            int r = (2 * w + rt) * 16 + c;
            int j0 = jt * 16 + hi * 4;
            uint64_t pk = 0;
#pragma unroll
            for (int e = 0; e < 4; ++e) pk |= (uint64_t)f2bf(acc[jt][rt][e]) << (16 * e);
            *(uint64_t*)&xsk[r * 128 + (j0 ^ ((r & 7) << 3))] = pk;
        }
    __syncthreads();

    // Wo fragments loaded late
    s16x8 bfO[2][4];
#pragma unroll
    for (int ot = 0; ot < 2; ++ot) {
        int o = (2 * w + ot) * 16 + c;
#pragma unroll
        for (int ks = 0; ks < 4; ++ks)
            bfO[ot][ks] = *(const s16x8*)&Wo16[o * 128 + ks * 32 + hi * 8];
    }

    // GEMM2: Out[r][o] = sum_j U^T[r,j] Wo[o,j]
    f32x4 acc2[8][2] = {};
#pragma unroll
    for (int rt8 = 0; rt8 < 8; ++rt8) {
        int rr = rt8 * 16 + c;
        s16x8 af[4];
#pragma unroll
        for (int ks = 0; ks < 4; ++ks)
            af[ks] = *(const s16x8*)&xsk[rr * 128 + ((ks * 32 + hi * 8) ^ ((rr & 7) << 3))];
#pragma unroll
        for (int ot = 0; ot < 2; ++ot)
#pragma unroll
            for (int ks = 0; ks < 4; ++ks)
                acc2[rt8][ot] = __builtin_amdgcn_mfma_f32_16x16x32_bf16(af[ks], bfO[ot][ks], acc2[rt8][ot], 0, 0, 0);
    }

    // epilogue
#pragma unroll
    for (int rt8 = 0; rt8 < 8; ++rt8)
#pragma unroll
        for (int ot = 0; ot < 2; ++ot)
#pragma unroll
            for (int e = 0; e < 4; ++e) {
                int r = rt8 * 16 + hi * 4 + e;
                int o = (2 * w + ot) * 16 + c;
                float val = acc2[rt8][ot][e] + csl[r] * wsl[o] + bol[o];
                out[((long)r * ngrp + p) * 128 + o] = val;
            }
}

// ------------------------------------------------------------------- launcher
extern "C" void kernel_launch(void* const* d_in, const int* in_sizes, int n_in,
                              void* d_out, int out_size, void* d_ws, size_t ws_size,
                              hipStream_t stream) {
    const float* x  = (const float*)d_in[0];
    const float* Wq = (const float*)d_in[1];
    const float* bq = (const float*)d_in[2];
    const float* Wk = (const float*)d_in[3];
    const float* bk = (const float*)d_in[4];
    const float* Wv = (const float*)d_in[5];
    const float* bv = (const float*)d_in[6];
    const float* Wo = (const float*)d_in[7];
    const float* bo = (const float*)d_in[8];
    float* out = (float*)d_out;
    float* ws = (float*)d_ws;

    int Bn   = in_sizes[0] / DD;   // 262144
    int ngrp = Bn / DD;            // 2048
    int nb1  = Bn / GROWS;         // 256

    float* parts = ws;
    float* G     = ws + (size_t)nb1 * PART_STRIDE;
    float* svec  = G + 16384;
    float* cvec  = svec + 128;
    float* wsumv = cvec + 128;
    unsigned short* M16  = (unsigned short*)(wsumv + 128);
    unsigned short* Wo16 = M16 + 16384;

    hipLaunchKernelGGL(k_gram, dim3(nb1), dim3(256), 0, stream, x, ws);
    hipLaunchKernelGGL(k_reduce, dim3(513), dim3(256), 0, stream,
                       ws, G, svec, nb1);
    hipLaunchKernelGGL(k_mid, dim3(128), dim3(256), 0, stream,
                       G, svec, Wq, bq, Wk, bk, Wv, bv, Wo,
                       M16, Wo16, cvec, wsumv, (float)Bn);
    hipLaunchKernelGGL(k_out32, dim3(ngrp), dim3(256), 0, stream,
                       x, M16, Wo16, cvec, wsumv, bo, out, ngrp);
}